// Round 4
// baseline (595.457 us; speedup 1.0000x reference)
//
#include <hip/hip_runtime.h>
#include <hip/hip_fp16.h>
#include <stdint.h>

#define LT 512   // timesteps
#define NB 512   // batch
#define DI 128   // input dim
#define DH 128   // hidden dim

typedef _Float16 f16;
typedef __attribute__((ext_vector_type(2))) _Float16 f16x2;
typedef __attribute__((ext_vector_type(8))) _Float16 f16x8;
typedef __attribute__((ext_vector_type(4))) float floatx4;

__device__ __forceinline__ uint32_t pack2(float x, float y) {
    f16x2 p;
    p.x = (_Float16)x;
    p.y = (_Float16)y;
    return __builtin_bit_cast(uint32_t, p);
}

__device__ __forceinline__ float frcp(float x) {
#if __has_builtin(__builtin_amdgcn_rcpf)
    return __builtin_amdgcn_rcpf(x);   // ~1ulp, absmax budget 0.0078
#else
    return 1.f / x;
#endif
}

__device__ __forceinline__ float sigm(float v) {
    return frcp(1.f + __expf(-v));
}

__device__ __forceinline__ float tanh_(float v) {
    float a = fabsf(v);
    float e = __expf(-2.f * a);
    float r = (1.f - e) * frcp(1.f + e);
    return v < 0.f ? -r : r;
}

// ============================================================================
// Fully fused LSTM v2: K-split recurrence + in-kernel x-gate precompute bursts.
// 256 blocks (1/CU) x 512 thr (8 waves). Block owns batch rows n0, n0+1.
//
// Per step (recurrent): gates_h = (h(t-1)*m(t)) . Whh^T via K=128 MFMA
//   -> 128 MFMA/block-step (was 256 with K=256).           [621 cyc floor]
// Every 8th step (burst): all 16 M-rows = x(t+8..t+15) x {n0,n1} ->
//   x.Wih^T for 8 future steps at FULL M-efficiency, 128 MFMA per 8 steps
//   (amortized 16/step). Results -> 16-slot LDS ring (f16, bias in f32 at
//   consume = identical numerics to verified round-1/2 gx path).
// B-frags: Whh (64 VGPR) + Wih (64 VGPR) both register-resident.
// x staging: 64 lanes, 2-step-deep register pipeline (~2 step-walls of HBM
//   cover) into double-buffered LDS x-stage; burst never touches HBM.
// Barrier: s_waitcnt lgkmcnt(0) + raw s_barrier -- NO vmcnt(0) drain, so
//   out-stores and x-prefetch stay in flight across steps (vs __syncthreads).
// ============================================================================
__launch_bounds__(512, 2)
__global__ void lstm_fused_v2(const float* __restrict__ x,
                              const float* __restrict__ hc0,
                              const int*   __restrict__ isini,
                              const float* __restrict__ Wih,
                              const float* __restrict__ Whh,
                              const float* __restrict__ bih,
                              const float* __restrict__ bhh,
                              float* __restrict__ out)
{
    const int tid  = threadIdx.x;
    const int lane = tid & 63;
    const int w    = tid >> 6;       // wave 0..7
    const int l16  = lane & 15;
    const int quad = lane >> 4;
    const int n0   = blockIdx.x * 2;
    const int j    = w * 16 + l16;   // hidden unit 0..127

    __shared__ __align__(16) f16   sh_h[2][2][136];   // [buf][row][k], 1.1 KB
    __shared__ __align__(16) f16   xs[2][16][136];    // x-stage dbuf, 8.7 KB
    __shared__ __align__(16) uint2 ring[16][2][128];  // x-gates ring, 32 KB
    __shared__ float sh_m[2][LT];                     // masks, 4 KB

    // ---- stage masks (1 element/thread/row) ----
    sh_m[0][tid] = 1.f - (float)isini[(size_t)tid * NB + n0];
    sh_m[1][tid] = 1.f - (float)isini[(size_t)tid * NB + n0 + 1];

    // ---- B-frags: Whh (recurrent) + Wih (burst), gate = gs*128+j ----
    f16x8 bH[4][4], bI[4][4];
    float bs[4];
#pragma unroll
    for (int gs = 0; gs < 4; ++gs) {
        const int gate = gs * 128 + j;
        bs[gs] = bih[gate] + bhh[gate];
        const float4* wh = (const float4*)(Whh + (size_t)gate * DH);
        const float4* wi = (const float4*)(Wih + (size_t)gate * DI);
#pragma unroll
        for (int kc = 0; kc < 4; ++kc) {
            float4 a = wh[kc * 8 + quad * 2];
            float4 b = wh[kc * 8 + quad * 2 + 1];
            uint4 u;
            u.x = pack2(a.x, a.y); u.y = pack2(a.z, a.w);
            u.z = pack2(b.x, b.y); u.w = pack2(b.z, b.w);
            bH[gs][kc] = __builtin_bit_cast(f16x8, u);
            a = wi[kc * 8 + quad * 2];
            b = wi[kc * 8 + quad * 2 + 1];
            u.x = pack2(a.x, a.y); u.y = pack2(a.z, a.w);
            u.z = pack2(b.x, b.y); u.w = pack2(b.z, b.w);
            bI[gs][kc] = __builtin_bit_cast(f16x8, u);
        }
    }

    // ---- stage x(0..7) -> xs[0]: 1 float4/thread, row m = d*2+nr ----
    {
        const int m = tid >> 5, f4 = tid & 31;
        const int d = m >> 1, nrr = m & 1;
        const float4* sp = (const float4*)(x + ((size_t)d * NB + n0 + nrr) * DI);
        float4 v = sp[f4];
        uint2 u2; u2.x = pack2(v.x, v.y); u2.y = pack2(v.z, v.w);
        *(uint2*)&xs[0][m][f4 * 4] = u2;
    }
    __syncthreads();   // masks + xs[0] visible

    // active lanes for state: quad 0 -> n0, quad 2 -> n1 (C row 0 / 8, reg 0)
    const bool act = (quad & 1) == 0;
    const int  nr  = quad >> 1;
    const int  n   = n0 + nr;
    const int  rowsel = l16 >> 3;    // recurrent A rows 0-7 <- n0, 8-15 <- n1

    float hval = 0.f, cval = 0.f, mcur = 0.f;
    if (act) {
        hval = hc0[(size_t)n * (2 * DH) + j];
        cval = hc0[(size_t)n * (2 * DH) + DH + j];
        mcur = sh_m[nr][0];
        sh_h[0][nr][j] = (f16)(hval * mcur);   // pre-masked h
    }

    // ---- prologue burst: ring slots 0..7 from xs[0] (x(0..7)) ----
    {
        const uint4* xb = (const uint4*)&xs[0][0][0];
        f16x8 axf[4];
#pragma unroll
        for (int kc = 0; kc < 4; ++kc)
            axf[kc] = __builtin_bit_cast(f16x8, xb[l16 * 17 + kc * 4 + quad]);
        floatx4 a2[4];
#pragma unroll
        for (int gs = 0; gs < 4; ++gs) a2[gs] = (floatx4){0.f, 0.f, 0.f, 0.f};
#pragma unroll
        for (int kc = 0; kc < 4; ++kc)
#pragma unroll
            for (int gs = 0; gs < 4; ++gs)
                a2[gs] = __builtin_amdgcn_mfma_f32_16x16x32_f16(
                    axf[kc], bI[gs][kc], a2[gs], 0, 0, 0);
#pragma unroll
        for (int r = 0; r < 4; ++r) {
            const int m = quad * 4 + r;
            uint2 u;
            u.x = pack2(a2[0][r], a2[1][r]);
            u.y = pack2(a2[2][r], a2[3][r]);
            ring[(m >> 1) & 15][m & 1][j] = u;
        }
    }

    // ---- stage x(8..15) -> xs[1] ----
    {
        const int m = tid >> 5, f4 = tid & 31;
        const int d = m >> 1, nrr = m & 1;
        const float4* sp = (const float4*)(x + ((size_t)(8 + d) * NB + n0 + nrr) * DI);
        float4 v = sp[f4];
        uint2 u2; u2.x = pack2(v.x, v.y); u2.y = pack2(v.z, v.w);
        *(uint2*)&xs[1][m][f4 * 4] = u2;
    }

    // ---- staging lanes: 2-step-deep x prefetch pipeline ----
    const int  sflat = w * 8 + (lane & 7);   // 0..63
    const int  srow  = sflat >> 5;           // 0 or 1
    const int  sf4   = sflat & 31;           // float4 idx in row
    const bool sact  = (lane < 8);
    float4 xp0 = {0.f, 0.f, 0.f, 0.f}, xp1 = {0.f, 0.f, 0.f, 0.f};
    if (sact) {
        xp0 = ((const float4*)(x + ((size_t)16 * NB + n0 + srow) * DI))[sf4];
        xp1 = ((const float4*)(x + ((size_t)17 * NB + n0 + srow) * DI))[sf4];
    }
    __syncthreads();

    float* outp = out + (size_t)n * DH + j;

    for (int t = 0; t < LT; ++t) {
        // ---- burst: x-gates for steps t+8..t+15 (every 8th step) ----
        if ((t & 7) == 0 && t + 8 < LT) {
            const uint4* xb = (const uint4*)&xs[((t >> 3) + 1) & 1][0][0];
            f16x8 axf[4];
#pragma unroll
            for (int kc = 0; kc < 4; ++kc)
                axf[kc] = __builtin_bit_cast(f16x8, xb[l16 * 17 + kc * 4 + quad]);
            floatx4 a2[4];
#pragma unroll
            for (int gs = 0; gs < 4; ++gs) a2[gs] = (floatx4){0.f, 0.f, 0.f, 0.f};
#pragma unroll
            for (int kc = 0; kc < 4; ++kc)
#pragma unroll
                for (int gs = 0; gs < 4; ++gs)
                    a2[gs] = __builtin_amdgcn_mfma_f32_16x16x32_f16(
                        axf[kc], bI[gs][kc], a2[gs], 0, 0, 0);
            const int tb = t + 8;
#pragma unroll
            for (int r = 0; r < 4; ++r) {
                const int m = quad * 4 + r;
                uint2 u;
                u.x = pack2(a2[0][r], a2[1][r]);
                u.y = pack2(a2[2][r], a2[3][r]);
                ring[(tb + (m >> 1)) & 15][m & 1][j] = u;
            }
        }

        // ---- x staging: write x(t+16) (loaded 2 steps ago), load x(t+18) ----
        if (sact) {
            uint2 u2; u2.x = pack2(xp0.x, xp0.y); u2.y = pack2(xp0.z, xp0.w);
            *(uint2*)&xs[(t >> 3) & 1][2 * (t & 7) + srow][sf4 * 4] = u2;
            xp0 = xp1;
            const int tl = t + 18;
            if (tl < LT)
                xp1 = ((const float4*)(x + ((size_t)tl * NB + n0 + srow) * DI))[sf4];
        }

        // ---- recurrent: (h*m) . Whh^T, K=128 -> 16 MFMA/wave ----
        const uint4* hb = (const uint4*)&sh_h[t & 1][0][0];
        f16x8 af[4];
#pragma unroll
        for (int kc = 0; kc < 4; ++kc)
            af[kc] = __builtin_bit_cast(f16x8, hb[rowsel * 17 + kc * 4 + quad]);
        floatx4 acc[4];
#pragma unroll
        for (int gs = 0; gs < 4; ++gs) acc[gs] = (floatx4){0.f, 0.f, 0.f, 0.f};
#pragma unroll
        for (int kc = 0; kc < 4; ++kc)
#pragma unroll
            for (int gs = 0; gs < 4; ++gs)
                acc[gs] = __builtin_amdgcn_mfma_f32_16x16x32_f16(
                    af[kc], bH[gs][kc], acc[gs], 0, 0, 0);

        // ---- lane-local nonlinearity (quads 0,2) ----
        if (act) {
            const uint2 rv = ring[t & 15][nr][j];
            const f16x2 p01 = __builtin_bit_cast(f16x2, rv.x);
            const f16x2 p23 = __builtin_bit_cast(f16x2, rv.y);
            float ig = (float)p01.x + bs[0] + acc[0][0];
            float fg = (float)p01.y + bs[1] + acc[1][0];
            float gg = (float)p23.x + bs[2] + acc[2][0];
            float og = (float)p23.y + bs[3] + acc[3][0];
            float cc = sigm(fg) * (mcur * cval) + sigm(ig) * tanh_(gg);
            hval = sigm(og) * tanh_(cc);
            cval = cc;
            outp[(size_t)t * (NB * DH)] = hval;
            const int t1 = (t + 1 < LT) ? (t + 1) : (LT - 1);
            const float mn = sh_m[nr][t1];
            sh_h[(t + 1) & 1][nr][j] = (f16)(hval * mn);   // pre-masked
            mcur = mn;
        }

        // ---- barrier WITHOUT vmcnt drain: LDS ordered, stores fly free ----
        asm volatile("s_waitcnt lgkmcnt(0)" ::: "memory");
        __builtin_amdgcn_s_barrier();
    }

    if (act) {
        size_t base = (size_t)LT * NB * DH;
        out[base + (size_t)n * (2 * DH) + j]      = hval;
        out[base + (size_t)n * (2 * DH) + DH + j] = cval;
    }
}

extern "C" void kernel_launch(void* const* d_in, const int* in_sizes, int n_in,
                              void* d_out, int out_size, void* d_ws, size_t ws_size,
                              hipStream_t stream) {
    const float* x     = (const float*)d_in[0];
    const float* hc0   = (const float*)d_in[1];
    const int*   isini = (const int*)d_in[2];
    const float* Wih   = (const float*)d_in[3];
    const float* Whh   = (const float*)d_in[4];
    const float* bih   = (const float*)d_in[5];
    const float* bhh   = (const float*)d_in[6];
    float* out = (float*)d_out;

    lstm_fused_v2<<<dim3(NB / 2), dim3(512), 0, stream>>>(
        x, hc0, isini, Wih, Whh, bih, bhh, out);
}